// Round 1
// baseline (1814.408 us; speedup 1.0000x reference)
//
#include <hip/hip_runtime.h>
#include <math.h>

#define B_ROWS 8192
#define IN_DIM 1024
#define HID_DIM 1024
#define OUT_DIM 256
#define M_DIM 1280   // HID + OUT
#define P_DIM 2304   // IN + M
#define TBLK 128
#define NBLK (M_DIM / TBLK)  // 10

// ---------------- GEMM: C[m][n] (+)= sum_k A[m][k] * B[n][k] (+ bias[n]) ----
#define BMT 128
#define BNT 128
#define BKT 16

__global__ __launch_bounds__(256)
void gemm_nt(const float* __restrict__ A, int lda,
             const float* __restrict__ Bmat, int ldb,
             float* __restrict__ C, int ldc, int K,
             const float* __restrict__ bias, int accumulate)
{
    __shared__ float As[BKT][BMT];
    __shared__ float Bs[BKT][BNT];
    const int bm = blockIdx.x * BMT;
    const int bn = blockIdx.y * BNT;
    const int tid = threadIdx.x;
    const int tx = tid & 15;
    const int ty = tid >> 4;

    float acc[2][2][4][4];
#pragma unroll
    for (int i = 0; i < 2; ++i)
#pragma unroll
        for (int j = 0; j < 2; ++j)
#pragma unroll
            for (int r = 0; r < 4; ++r)
#pragma unroll
                for (int c = 0; c < 4; ++c) acc[i][j][r][c] = 0.f;

    for (int k0 = 0; k0 < K; k0 += BKT) {
#pragma unroll
        for (int i = 0; i < 2; ++i) {
            int lin = tid * 2 + i;        // 0..511
            int r   = lin >> 2;           // 0..127
            int kk  = (lin & 3) << 2;     // 0,4,8,12
            float4 va = *(const float4*)(A + (size_t)(bm + r) * lda + (k0 + kk));
            As[kk + 0][r] = va.x; As[kk + 1][r] = va.y;
            As[kk + 2][r] = va.z; As[kk + 3][r] = va.w;
            float4 vb = *(const float4*)(Bmat + (size_t)(bn + r) * ldb + (k0 + kk));
            Bs[kk + 0][r] = vb.x; Bs[kk + 1][r] = vb.y;
            Bs[kk + 2][r] = vb.z; Bs[kk + 3][r] = vb.w;
        }
        __syncthreads();
#pragma unroll
        for (int k = 0; k < BKT; ++k) {
            float4 a0 = *(const float4*)&As[k][ty * 4];
            float4 a1 = *(const float4*)&As[k][64 + ty * 4];
            float4 b0 = *(const float4*)&Bs[k][tx * 4];
            float4 b1 = *(const float4*)&Bs[k][64 + tx * 4];
            float ar[2][4] = {{a0.x, a0.y, a0.z, a0.w}, {a1.x, a1.y, a1.z, a1.w}};
            float br[2][4] = {{b0.x, b0.y, b0.z, b0.w}, {b1.x, b1.y, b1.z, b1.w}};
#pragma unroll
            for (int i = 0; i < 2; ++i)
#pragma unroll
                for (int r = 0; r < 4; ++r)
#pragma unroll
                    for (int j = 0; j < 2; ++j)
#pragma unroll
                        for (int c = 0; c < 4; ++c)
                            acc[i][j][r][c] += ar[i][r] * br[j][c];
        }
        __syncthreads();
    }

#pragma unroll
    for (int i = 0; i < 2; ++i) {
#pragma unroll
        for (int r = 0; r < 4; ++r) {
            int m = bm + i * 64 + ty * 4 + r;
#pragma unroll
            for (int j = 0; j < 2; ++j) {
                int n = bn + j * 64 + tx * 4;
                float4* cp = (float4*)(C + (size_t)m * ldc + n);
                float4 v;
                v.x = acc[i][j][r][0]; v.y = acc[i][j][r][1];
                v.z = acc[i][j][r][2]; v.w = acc[i][j][r][3];
                if (bias) {
                    v.x += bias[n]; v.y += bias[n + 1];
                    v.z += bias[n + 2]; v.w += bias[n + 3];
                }
                if (accumulate) {
                    float4 old = *cp;
                    v.x += old.x; v.y += old.y; v.z += old.z; v.w += old.w;
                }
                *cp = v;
            }
        }
    }
}

// -------- within-block sequential recurrence: one wave = 64 batch rows ------
// S holds: pre-activation (accumulated) for future cols, h for completed cols.
__global__ __launch_bounds__(64)
void seq_block(float* __restrict__ S, const float* __restrict__ W, int j0)
{
    __shared__ float  WhL[TBLK][TBLK];     // 64 KB  WhL[t][s] = W[j0+t][IN+j0+s]
    __shared__ float  Sl[TBLK][64];        // 32 KB  Sl[t][row] pre-activations
    __shared__ float4 H4[TBLK / 4][64];    // 32 KB  per-lane h history (chunks of 4)
    const int lane = threadIdx.x;
    const int row0 = blockIdx.x * 64;

    for (int idx = lane; idx < TBLK * TBLK; idx += 64) {
        int t = idx >> 7;            // /TBLK
        int s = idx & (TBLK - 1);
        WhL[t][s] = W[(size_t)(j0 + t) * P_DIM + (IN_DIM + j0 + s)];
    }
    for (int r = 0; r < 64; ++r) {
        float2 v = *(const float2*)(S + (size_t)(row0 + r) * M_DIM + j0 + lane * 2);
        Sl[lane * 2][r]     = v.x;
        Sl[lane * 2 + 1][r] = v.y;
    }
    __syncthreads();

    float* Hf = (float*)H4;  // flat idx: chunk*256 + lane*4 + comp
    for (int t = 0; t < TBLK; ++t) {
        float a0 = 0.f, a1 = 0.f, a2 = 0.f, a3 = 0.f;
        const float* wr = &WhL[t][0];
        const int nc = t >> 2;
        for (int c = 0; c < nc; ++c) {
            float4 hv = H4[c][lane];
            a0 += wr[c * 4 + 0] * hv.x;
            a1 += wr[c * 4 + 1] * hv.y;
            a2 += wr[c * 4 + 2] * hv.z;
            a3 += wr[c * 4 + 3] * hv.w;
        }
        float accv = Sl[t][lane] + ((a0 + a1) + (a2 + a3));
        for (int s = nc * 4; s < t; ++s)
            accv += wr[s] * Hf[(s >> 2) * 256 + lane * 4 + (s & 3)];
        float hvn = tanhf(accv);
        Hf[(t >> 2) * 256 + lane * 4 + (t & 3)] = hvn;
    }
    __syncthreads();

    for (int r = 0; r < 64; ++r) {
        int c0 = lane * 2, c1 = lane * 2 + 1;
        float2 o;
        o.x = Hf[(c0 >> 2) * 256 + r * 4 + (c0 & 3)];
        o.y = Hf[(c1 >> 2) * 256 + r * 4 + (c1 & 3)];
        *(float2*)(S + (size_t)(row0 + r) * M_DIM + j0 + lane * 2) = o;
    }
}

// ---------------- epilogue: out = sigmoid(S[:, HID : HID+OUT]) --------------
__global__ __launch_bounds__(256)
void out_sigmoid(const float* __restrict__ S, float* __restrict__ out)
{
    int idx = blockIdx.x * blockDim.x + threadIdx.x;
    if (idx >= B_ROWS * OUT_DIM) return;
    int b = idx >> 8;       // /OUT_DIM
    int o = idx & (OUT_DIM - 1);
    float y = S[(size_t)b * M_DIM + HID_DIM + o];
    out[idx] = 1.f / (1.f + expf(-y));
}

extern "C" void kernel_launch(void* const* d_in, const int* in_sizes, int n_in,
                              void* d_out, int out_size, void* d_ws, size_t ws_size,
                              hipStream_t stream)
{
    const float* x    = (const float*)d_in[0];   // (8192, 1024)
    const float* W    = (const float*)d_in[1];   // (1280, 2304)
    const float* bias = (const float*)d_in[2];   // (1280,)
    float* out = (float*)d_out;
    float* S   = (float*)d_ws;                   // (8192, 1280) f32 = 41.9 MB

    // 1) pre-activations from x: S = x @ Wx^T + b
    gemm_nt<<<dim3(B_ROWS / BMT, M_DIM / BNT), dim3(256), 0, stream>>>(
        x, IN_DIM, W, P_DIM, S, M_DIM, IN_DIM, bias, 0);

    // 2) blocked triangular recurrence
    for (int J = 0; J < NBLK; ++J) {
        int j0 = J * TBLK;
        seq_block<<<dim3(B_ROWS / 64), dim3(64), 0, stream>>>(S, W, j0);
        int nfut = M_DIM - j0 - TBLK;
        if (nfut > 0) {
            // S[:, fut] += S[:, blk] @ Wh[fut, blk]^T
            gemm_nt<<<dim3(B_ROWS / BMT, nfut / BNT), dim3(256), 0, stream>>>(
                S + j0, M_DIM,
                W + (size_t)(j0 + TBLK) * P_DIM + IN_DIM + j0, P_DIM,
                S + j0 + TBLK, M_DIM, TBLK, nullptr, 1);
        }
    }

    // 3) output
    int total = B_ROWS * OUT_DIM;
    out_sigmoid<<<dim3((total + 255) / 256), dim3(256), 0, stream>>>(S, out);
}

// Round 2
// 1629.731 us; speedup vs baseline: 1.1133x; 1.1133x over previous
//
#include <hip/hip_runtime.h>
#include <math.h>

#define B_ROWS 8192
#define IN_DIM 1024
#define HID_DIM 1024
#define OUT_DIM 256
#define M_DIM 1280   // HID + OUT
#define P_DIM 2304   // IN + M
#define TBLK 128
#define NBLK (M_DIM / TBLK)  // 10
#define LWP 132              // padded row stride (16B-aligned rows, conflict-free-ish)

// ---------------- GEMM: C[m][n] (+)= sum_k A[m][k] * B[n][k] (+ bias[n]) ----
#define BMT 128
#define BNT 128
#define BKT 16

__global__ __launch_bounds__(256)
void gemm_nt(const float* __restrict__ A, int lda,
             const float* __restrict__ Bmat, int ldb,
             float* __restrict__ C, int ldc, int K,
             const float* __restrict__ bias, int accumulate)
{
    __shared__ float As[BKT][BMT];
    __shared__ float Bs[BKT][BNT];
    const int bm = blockIdx.x * BMT;
    const int bn = blockIdx.y * BNT;
    const int tid = threadIdx.x;
    const int tx = tid & 15;
    const int ty = tid >> 4;

    float acc[2][2][4][4];
#pragma unroll
    for (int i = 0; i < 2; ++i)
#pragma unroll
        for (int j = 0; j < 2; ++j)
#pragma unroll
            for (int r = 0; r < 4; ++r)
#pragma unroll
                for (int c = 0; c < 4; ++c) acc[i][j][r][c] = 0.f;

    for (int k0 = 0; k0 < K; k0 += BKT) {
#pragma unroll
        for (int i = 0; i < 2; ++i) {
            int lin = tid * 2 + i;        // 0..511
            int r   = lin >> 2;           // 0..127
            int kk  = (lin & 3) << 2;     // 0,4,8,12
            float4 va = *(const float4*)(A + (size_t)(bm + r) * lda + (k0 + kk));
            As[kk + 0][r] = va.x; As[kk + 1][r] = va.y;
            As[kk + 2][r] = va.z; As[kk + 3][r] = va.w;
            float4 vb = *(const float4*)(Bmat + (size_t)(bn + r) * ldb + (k0 + kk));
            Bs[kk + 0][r] = vb.x; Bs[kk + 1][r] = vb.y;
            Bs[kk + 2][r] = vb.z; Bs[kk + 3][r] = vb.w;
        }
        __syncthreads();
#pragma unroll
        for (int k = 0; k < BKT; ++k) {
            float4 a0 = *(const float4*)&As[k][ty * 4];
            float4 a1 = *(const float4*)&As[k][64 + ty * 4];
            float4 b0 = *(const float4*)&Bs[k][tx * 4];
            float4 b1 = *(const float4*)&Bs[k][64 + tx * 4];
            float ar[2][4] = {{a0.x, a0.y, a0.z, a0.w}, {a1.x, a1.y, a1.z, a1.w}};
            float br[2][4] = {{b0.x, b0.y, b0.z, b0.w}, {b1.x, b1.y, b1.z, b1.w}};
#pragma unroll
            for (int i = 0; i < 2; ++i)
#pragma unroll
                for (int r = 0; r < 4; ++r)
#pragma unroll
                    for (int j = 0; j < 2; ++j)
#pragma unroll
                        for (int c = 0; c < 4; ++c)
                            acc[i][j][r][c] += ar[i][r] * br[j][c];
        }
        __syncthreads();
    }

#pragma unroll
    for (int i = 0; i < 2; ++i) {
#pragma unroll
        for (int r = 0; r < 4; ++r) {
            int m = bm + i * 64 + ty * 4 + r;
#pragma unroll
            for (int j = 0; j < 2; ++j) {
                int n = bn + j * 64 + tx * 4;
                float4* cp = (float4*)(C + (size_t)m * ldc + n);
                float4 v;
                v.x = acc[i][j][r][0]; v.y = acc[i][j][r][1];
                v.z = acc[i][j][r][2]; v.w = acc[i][j][r][3];
                if (bias) {
                    v.x += bias[n]; v.y += bias[n + 1];
                    v.z += bias[n + 2]; v.w += bias[n + 3];
                }
                if (accumulate) {
                    float4 old = *cp;
                    v.x += old.x; v.y += old.y; v.z += old.z; v.w += old.w;
                }
                *cp = v;
            }
        }
    }
}

// fast tanh: (e^{2x}-1)/(e^{2x}+1) with hw exp + hw rcp. |err| ~1e-6.
__device__ __forceinline__ float tanh_fast(float x)
{
    x = fminf(fmaxf(x, -15.f), 15.f);
    float e = __expf(2.f * x);
    return (e - 1.f) * __builtin_amdgcn_rcpf(e + 1.f);
}

// -------- within-block sequential recurrence, right-looking ------------------
// One wave per block, lane = batch row. acc[0..127] = this block's
// pre-activations in VGPRs (fully unrolled -> static indexing).
// Step t: h = tanh(acc[t]); acc[u] += LW[t][u]*h for u>t (LDS broadcast reads).
__global__ __launch_bounds__(64, 1)
void seq_block(float* __restrict__ S, const float* __restrict__ W, int j0)
{
    __shared__ float LW[TBLK][LWP];   // LW[s][u] = W[j0+u][IN+j0+s]; 66 KB
    const int lane = threadIdx.x;
    const int row  = blockIdx.x * 64 + lane;

    // load weight block, transposed: coalesced global float4 reads
    for (int idx = lane; idx < TBLK * TBLK / 4; idx += 64) {
        int u  = idx >> 5;            // 0..127
        int s4 = (idx & 31) << 2;     // 0,4,...,124
        float4 w = *(const float4*)(W + (size_t)(j0 + u) * P_DIM + (IN_DIM + j0 + s4));
        LW[s4 + 0][u] = w.x; LW[s4 + 1][u] = w.y;
        LW[s4 + 2][u] = w.z; LW[s4 + 3][u] = w.w;
    }

    // load this lane's row of pre-activations into registers
    float acc[TBLK];
    const float* Srow = S + (size_t)row * M_DIM + j0;
#pragma unroll
    for (int q = 0; q < TBLK / 4; ++q) {
        float4 v = *(const float4*)(Srow + q * 4);
        acc[q * 4 + 0] = v.x; acc[q * 4 + 1] = v.y;
        acc[q * 4 + 2] = v.z; acc[q * 4 + 3] = v.w;
    }
    __syncthreads();

#pragma unroll
    for (int t = 0; t < TBLK; ++t) {
        float h = tanh_fast(acc[t]);
        acc[t] = h;
        const int ua = (t + 4) & ~3;          // first 16B-aligned u after t
        const int uh = (ua < TBLK) ? ua : TBLK;
#pragma unroll
        for (int u = t + 1; u < uh; ++u)
            acc[u] += LW[t][u] * h;
#pragma unroll
        for (int u4 = ua; u4 < TBLK; u4 += 4) {
            float4 w = *(const float4*)&LW[t][u4];
            acc[u4 + 0] += w.x * h;
            acc[u4 + 1] += w.y * h;
            acc[u4 + 2] += w.z * h;
            acc[u4 + 3] += w.w * h;
        }
    }

    // write h values back
    float* Sout = S + (size_t)row * M_DIM + j0;
#pragma unroll
    for (int q = 0; q < TBLK / 4; ++q) {
        float4 v;
        v.x = acc[q * 4 + 0]; v.y = acc[q * 4 + 1];
        v.z = acc[q * 4 + 2]; v.w = acc[q * 4 + 3];
        *(float4*)(Sout + q * 4) = v;
    }
}

// ---------------- epilogue: out = sigmoid(S[:, HID : HID+OUT]) --------------
__global__ __launch_bounds__(256)
void out_sigmoid(const float* __restrict__ S, float* __restrict__ out)
{
    int idx = blockIdx.x * blockDim.x + threadIdx.x;
    if (idx >= B_ROWS * OUT_DIM) return;
    int b = idx >> 8;       // /OUT_DIM
    int o = idx & (OUT_DIM - 1);
    float y = S[(size_t)b * M_DIM + HID_DIM + o];
    out[idx] = 1.f / (1.f + expf(-y));
}

extern "C" void kernel_launch(void* const* d_in, const int* in_sizes, int n_in,
                              void* d_out, int out_size, void* d_ws, size_t ws_size,
                              hipStream_t stream)
{
    const float* x    = (const float*)d_in[0];   // (8192, 1024)
    const float* W    = (const float*)d_in[1];   // (1280, 2304)
    const float* bias = (const float*)d_in[2];   // (1280,)
    float* out = (float*)d_out;
    float* S   = (float*)d_ws;                   // (8192, 1280) f32 = 41.9 MB

    // 1) pre-activations from x: S = x @ Wx^T + b
    gemm_nt<<<dim3(B_ROWS / BMT, M_DIM / BNT), dim3(256), 0, stream>>>(
        x, IN_DIM, W, P_DIM, S, M_DIM, IN_DIM, bias, 0);

    // 2) blocked triangular recurrence
    for (int J = 0; J < NBLK; ++J) {
        int j0 = J * TBLK;
        seq_block<<<dim3(B_ROWS / 64), dim3(64), 0, stream>>>(S, W, j0);
        int nfut = M_DIM - j0 - TBLK;
        if (nfut > 0) {
            // S[:, fut] += S[:, blk] @ Wh[fut, blk]^T
            gemm_nt<<<dim3(B_ROWS / BMT, nfut / BNT), dim3(256), 0, stream>>>(
                S + j0, M_DIM,
                W + (size_t)(j0 + TBLK) * P_DIM + IN_DIM + j0, P_DIM,
                S + j0 + TBLK, M_DIM, TBLK, nullptr, 1);
        }
    }

    // 3) output
    int total = B_ROWS * OUT_DIM;
    out_sigmoid<<<dim3((total + 255) / 256), dim3(256), 0, stream>>>(S, out);
}

// Round 3
// 1366.875 us; speedup vs baseline: 1.3274x; 1.1923x over previous
//
#include <hip/hip_runtime.h>
#include <hip/hip_bf16.h>
#include <math.h>

typedef short short8 __attribute__((ext_vector_type(8)));
typedef float f32x4  __attribute__((ext_vector_type(4)));

#define B_ROWS 8192
#define IN_DIM 1024
#define HID_DIM 1024
#define OUT_DIM 256
#define M_DIM 1280   // HID + OUT
#define P_DIM 2304   // IN + M
#define TBLK 128
#define NBLK (M_DIM / TBLK)  // 10
#define LWP 132

// ---------------- bf16 MFMA GEMM: C[m][n] (+)= sum_k A[m][k]*B[n][k] (+bias)
// A, B are f32 in HBM, converted to bf16 during LDS staging. C is f32.
#define GBM 128
#define GBN 128
#define GBK 32
#define LDP 40   // LDS row stride (elems): 80B = 16B-aligned, non-pow2 (bank-friendly)

__device__ __forceinline__ short f2bf(float x)
{
    __hip_bfloat16 h = __float2bfloat16(x);
    return *(short*)&h;
}

__global__ __launch_bounds__(256)
void gemm_nt_mfma(const float* __restrict__ A, int lda,
                  const float* __restrict__ Bm, int ldb,
                  float* __restrict__ C, int ldc, int K,
                  const float* __restrict__ bias, int accumulate)
{
    __shared__ short As[GBM * LDP];
    __shared__ short Bs[GBN * LDP];
    const int tid  = threadIdx.x;
    const int lane = tid & 63;
    const int wid  = tid >> 6;
    const int wr   = wid >> 1;   // wave row (0..1), 64-row band
    const int wc   = wid & 1;    // wave col (0..1), 64-col band
    const int bm   = blockIdx.y * GBM;
    const int bn   = blockIdx.x * GBN;

    f32x4 acc[4][4];
#pragma unroll
    for (int m = 0; m < 4; ++m)
#pragma unroll
        for (int n = 0; n < 4; ++n)
            acc[m][n] = (f32x4){0.f, 0.f, 0.f, 0.f};

    const int rl = lane & 15;          // fragment row/col within 16
    const int kq = (lane >> 4) * 8;    // k-chunk offset within 32

    for (int k0 = 0; k0 < K; k0 += GBK) {
        __syncthreads();
        // stage A and B tiles (f32 -> bf16), 2 chunks of 8 elems each
#pragma unroll
        for (int h = 0; h < 2; ++h) {
            int c  = tid + h * 256;       // 0..511
            int r  = c >> 2;              // 0..127
            int co = (c & 3) << 3;        // 0,8,16,24
            const float* ga = A + (size_t)(bm + r) * lda + k0 + co;
            float4 a0 = *(const float4*)ga;
            float4 a1 = *(const float4*)(ga + 4);
            short8 sa;
            sa[0] = f2bf(a0.x); sa[1] = f2bf(a0.y); sa[2] = f2bf(a0.z); sa[3] = f2bf(a0.w);
            sa[4] = f2bf(a1.x); sa[5] = f2bf(a1.y); sa[6] = f2bf(a1.z); sa[7] = f2bf(a1.w);
            *(short8*)&As[r * LDP + co] = sa;
            const float* gb = Bm + (size_t)(bn + r) * ldb + k0 + co;
            float4 b0 = *(const float4*)gb;
            float4 b1 = *(const float4*)(gb + 4);
            short8 sb;
            sb[0] = f2bf(b0.x); sb[1] = f2bf(b0.y); sb[2] = f2bf(b0.z); sb[3] = f2bf(b0.w);
            sb[4] = f2bf(b1.x); sb[5] = f2bf(b1.y); sb[6] = f2bf(b1.z); sb[7] = f2bf(b1.w);
            *(short8*)&Bs[r * LDP + co] = sb;
        }
        __syncthreads();

        short8 af[4], bfr[4];
#pragma unroll
        for (int m = 0; m < 4; ++m)
            af[m] = *(const short8*)&As[(wr * 64 + m * 16 + rl) * LDP + kq];
#pragma unroll
        for (int n = 0; n < 4; ++n)
            bfr[n] = *(const short8*)&Bs[(wc * 64 + n * 16 + rl) * LDP + kq];
#pragma unroll
        for (int m = 0; m < 4; ++m)
#pragma unroll
            for (int n = 0; n < 4; ++n)
                acc[m][n] = __builtin_amdgcn_mfma_f32_16x16x32_bf16(
                    af[m], bfr[n], acc[m][n], 0, 0, 0);
    }

    // epilogue: lane holds rows (lane>>4)*4 + r, col lane&15 of each 16x16 frag
    const int rq = (lane >> 4) * 4;
#pragma unroll
    for (int m = 0; m < 4; ++m) {
#pragma unroll
        for (int n = 0; n < 4; ++n) {
            int row = bm + wr * 64 + m * 16 + rq;
            int col = bn + wc * 64 + n * 16 + rl;
            float* cp = C + (size_t)row * ldc + col;
            float bv = bias ? bias[col] : 0.f;
            f32x4 v = acc[m][n];
#pragma unroll
            for (int r = 0; r < 4; ++r) {
                float val = v[r] + bv;
                if (accumulate) val += cp[(size_t)r * ldc];
                cp[(size_t)r * ldc] = val;
            }
        }
    }
}

// fast tanh: (e^{2x}-1)/(e^{2x}+1) with hw exp + hw rcp. |err| ~1e-6.
__device__ __forceinline__ float tanh_fast(float x)
{
    x = fminf(fmaxf(x, -15.f), 15.f);
    float e = __expf(2.f * x);
    return (e - 1.f) * __builtin_amdgcn_rcpf(e + 1.f);
}

// -------- within-block sequential recurrence, right-looking ------------------
__global__ __launch_bounds__(64, 1)
void seq_block(float* __restrict__ S, const float* __restrict__ W, int j0)
{
    __shared__ float LW[TBLK][LWP];   // LW[s][u] = W[j0+u][IN+j0+s]
    const int lane = threadIdx.x;
    const int row  = blockIdx.x * 64 + lane;

    for (int idx = lane; idx < TBLK * TBLK / 4; idx += 64) {
        int u  = idx >> 5;
        int s4 = (idx & 31) << 2;
        float4 w = *(const float4*)(W + (size_t)(j0 + u) * P_DIM + (IN_DIM + j0 + s4));
        LW[s4 + 0][u] = w.x; LW[s4 + 1][u] = w.y;
        LW[s4 + 2][u] = w.z; LW[s4 + 3][u] = w.w;
    }

    float acc[TBLK];
    const float* Srow = S + (size_t)row * M_DIM + j0;
#pragma unroll
    for (int q = 0; q < TBLK / 4; ++q) {
        float4 v = *(const float4*)(Srow + q * 4);
        acc[q * 4 + 0] = v.x; acc[q * 4 + 1] = v.y;
        acc[q * 4 + 2] = v.z; acc[q * 4 + 3] = v.w;
    }
    __syncthreads();

#pragma unroll
    for (int t = 0; t < TBLK; ++t) {
        float h = tanh_fast(acc[t]);
        acc[t] = h;
        const int ua = (t + 4) & ~3;
        const int uh = (ua < TBLK) ? ua : TBLK;
#pragma unroll
        for (int u = t + 1; u < uh; ++u)
            acc[u] += LW[t][u] * h;
#pragma unroll
        for (int u4 = ua; u4 < TBLK; u4 += 4) {
            float4 w = *(const float4*)&LW[t][u4];
            acc[u4 + 0] += w.x * h;
            acc[u4 + 1] += w.y * h;
            acc[u4 + 2] += w.z * h;
            acc[u4 + 3] += w.w * h;
        }
    }

    float* Sout = S + (size_t)row * M_DIM + j0;
#pragma unroll
    for (int q = 0; q < TBLK / 4; ++q) {
        float4 v;
        v.x = acc[q * 4 + 0]; v.y = acc[q * 4 + 1];
        v.z = acc[q * 4 + 2]; v.w = acc[q * 4 + 3];
        *(float4*)(Sout + q * 4) = v;
    }
}

// ---------------- epilogue: out = sigmoid(S[:, HID : HID+OUT]) --------------
__global__ __launch_bounds__(256)
void out_sigmoid(const float* __restrict__ S, float* __restrict__ out)
{
    int idx = blockIdx.x * blockDim.x + threadIdx.x;
    if (idx >= B_ROWS * OUT_DIM) return;
    int b = idx >> 8;
    int o = idx & (OUT_DIM - 1);
    float y = S[(size_t)b * M_DIM + HID_DIM + o];
    out[idx] = 1.f / (1.f + expf(-y));
}

extern "C" void kernel_launch(void* const* d_in, const int* in_sizes, int n_in,
                              void* d_out, int out_size, void* d_ws, size_t ws_size,
                              hipStream_t stream)
{
    const float* x    = (const float*)d_in[0];   // (8192, 1024)
    const float* W    = (const float*)d_in[1];   // (1280, 2304)
    const float* bias = (const float*)d_in[2];   // (1280,)
    float* out = (float*)d_out;
    float* S   = (float*)d_ws;                   // (8192, 1280) f32 = 41.9 MB

    // 1) S = x @ Wx^T + b  (bf16 MFMA, f32 accumulate)
    gemm_nt_mfma<<<dim3(M_DIM / GBN, B_ROWS / GBM), dim3(256), 0, stream>>>(
        x, IN_DIM, W, P_DIM, S, M_DIM, IN_DIM, bias, 0);

    // 2) blocked triangular recurrence
    for (int J = 0; J < NBLK; ++J) {
        int j0 = J * TBLK;
        seq_block<<<dim3(B_ROWS / 64), dim3(64), 0, stream>>>(S, W, j0);
        int nfut = M_DIM - j0 - TBLK;
        if (nfut > 0) {
            // S[:, fut] += h_blk @ Wh[fut, blk]^T
            gemm_nt_mfma<<<dim3(nfut / GBN, B_ROWS / GBM), dim3(256), 0, stream>>>(
                S + j0, M_DIM,
                W + (size_t)(j0 + TBLK) * P_DIM + IN_DIM + j0, P_DIM,
                S + j0 + TBLK, M_DIM, TBLK, nullptr, 1);
        }
    }

    // 3) output
    int total = B_ROWS * OUT_DIM;
    out_sigmoid<<<dim3((total + 255) / 256), dim3(256), 0, stream>>>(S, out);
}

// Round 4
// 599.417 us; speedup vs baseline: 3.0270x; 2.2803x over previous
//
#include <hip/hip_runtime.h>
#include <hip/hip_bf16.h>
#include <math.h>

typedef short short8 __attribute__((ext_vector_type(8)));
typedef float f32x4  __attribute__((ext_vector_type(4)));

#define B_ROWS 8192
#define IN_DIM 1024
#define HID_DIM 1024
#define OUT_DIM 256
#define M_DIM 1280   // HID + OUT
#define P_DIM 2304   // IN + M
#define TBLK 128
#define NBLK (M_DIM / TBLK)  // 10
#define SEQ_WAVES 4
#define USLICE (TBLK / SEQ_WAVES)  // 32

// ---------------- bf16 MFMA GEMM: C[m][n] (+)= sum_k A[m][k]*B[n][k] (+bias)
#define GBM 128
#define GBN 128
#define GBK 32
#define LDP 40   // LDS row stride (elems)

__device__ __forceinline__ short f2bf(float x)
{
    __hip_bfloat16 h = __float2bfloat16(x);
    return *(short*)&h;
}

__global__ __launch_bounds__(256)
void gemm_nt_mfma(const float* __restrict__ A, int lda,
                  const float* __restrict__ Bm, int ldb,
                  float* __restrict__ C, int ldc, int K,
                  const float* __restrict__ bias, int accumulate)
{
    __shared__ short As[GBM * LDP];
    __shared__ short Bs[GBN * LDP];
    const int tid  = threadIdx.x;
    const int lane = tid & 63;
    const int wid  = tid >> 6;
    const int wr   = wid >> 1;
    const int wc   = wid & 1;
    const int bm   = blockIdx.y * GBM;
    const int bn   = blockIdx.x * GBN;

    f32x4 acc[4][4];
#pragma unroll
    for (int m = 0; m < 4; ++m)
#pragma unroll
        for (int n = 0; n < 4; ++n)
            acc[m][n] = (f32x4){0.f, 0.f, 0.f, 0.f};

    const int rl = lane & 15;
    const int kq = (lane >> 4) * 8;

    for (int k0 = 0; k0 < K; k0 += GBK) {
        __syncthreads();
#pragma unroll
        for (int h = 0; h < 2; ++h) {
            int c  = tid + h * 256;
            int r  = c >> 2;
            int co = (c & 3) << 3;
            const float* ga = A + (size_t)(bm + r) * lda + k0 + co;
            float4 a0 = *(const float4*)ga;
            float4 a1 = *(const float4*)(ga + 4);
            short8 sa;
            sa[0] = f2bf(a0.x); sa[1] = f2bf(a0.y); sa[2] = f2bf(a0.z); sa[3] = f2bf(a0.w);
            sa[4] = f2bf(a1.x); sa[5] = f2bf(a1.y); sa[6] = f2bf(a1.z); sa[7] = f2bf(a1.w);
            *(short8*)&As[r * LDP + co] = sa;
            const float* gb = Bm + (size_t)(bn + r) * ldb + k0 + co;
            float4 b0 = *(const float4*)gb;
            float4 b1 = *(const float4*)(gb + 4);
            short8 sb;
            sb[0] = f2bf(b0.x); sb[1] = f2bf(b0.y); sb[2] = f2bf(b0.z); sb[3] = f2bf(b0.w);
            sb[4] = f2bf(b1.x); sb[5] = f2bf(b1.y); sb[6] = f2bf(b1.z); sb[7] = f2bf(b1.w);
            *(short8*)&Bs[r * LDP + co] = sb;
        }
        __syncthreads();

        short8 af[4], bfr[4];
#pragma unroll
        for (int m = 0; m < 4; ++m)
            af[m] = *(const short8*)&As[(wr * 64 + m * 16 + rl) * LDP + kq];
#pragma unroll
        for (int n = 0; n < 4; ++n)
            bfr[n] = *(const short8*)&Bs[(wc * 64 + n * 16 + rl) * LDP + kq];
#pragma unroll
        for (int m = 0; m < 4; ++m)
#pragma unroll
            for (int n = 0; n < 4; ++n)
                acc[m][n] = __builtin_amdgcn_mfma_f32_16x16x32_bf16(
                    af[m], bfr[n], acc[m][n], 0, 0, 0);
    }

    const int rq = (lane >> 4) * 4;
#pragma unroll
    for (int m = 0; m < 4; ++m) {
#pragma unroll
        for (int n = 0; n < 4; ++n) {
            int row = bm + wr * 64 + m * 16 + rq;
            int col = bn + wc * 64 + n * 16 + rl;
            float* cp = C + (size_t)row * ldc + col;
            float bv = bias ? bias[col] : 0.f;
            f32x4 v = acc[m][n];
#pragma unroll
            for (int r = 0; r < 4; ++r) {
                float val = v[r] + bv;
                if (accumulate) val += cp[(size_t)r * ldc];
                cp[(size_t)r * ldc] = val;
            }
        }
    }
}

// fast tanh: (e^{2x}-1)/(e^{2x}+1) with hw exp + hw rcp. |err| ~1e-6.
__device__ __forceinline__ float tanh_fast(float x)
{
    x = fminf(fmaxf(x, -15.f), 15.f);
    float e = __expf(2.f * x);
    return (e - 1.f) * __builtin_amdgcn_rcpf(e + 1.f);
}

// -------- within-block sequential recurrence, 4-wave u-partitioned ----------
// 4 waves share the same 64 batch rows (lane = row). Wave w owns future-
// neuron slice u in [32w, 32w+32) in registers. LW[t][u] zeroed for u<=t so
// the per-step update is 32 blind FMAs. One barrier per step; h broadcast via
// double-buffered 64-float LDS slot.
__global__ __launch_bounds__(256, 1)
void seq_block(float* __restrict__ S, const float* __restrict__ W, int j0)
{
    __shared__ float LW[TBLK][TBLK];   // 64 KB; LW[t][u] = (u>t) ? W[j0+u][IN+j0+t] : 0
    __shared__ float hb[2][64];
    const int tid  = threadIdx.x;
    const int lane = tid & 63;
    const int w    = tid >> 6;
    const int row  = blockIdx.x * 64 + lane;

    // stage LW: lanes map to u (conflict-free LDS writes; strided global reads
    // hit L2 -- the 64 KB W block is shared by all 128 blocks).
    {
        const int u  = tid & 127;          // 0..127
        const int th = tid >> 7;           // 0..1
        for (int it = 0; it < 16; ++it) {
            int t4 = (it * 2 + th) * 4;    // 0,4,...,124
            float4 v = *(const float4*)(W + (size_t)(j0 + u) * P_DIM + (IN_DIM + j0 + t4));
            LW[t4 + 0][u] = (u > t4 + 0) ? v.x : 0.f;
            LW[t4 + 1][u] = (u > t4 + 1) ? v.y : 0.f;
            LW[t4 + 2][u] = (u > t4 + 2) ? v.z : 0.f;
            LW[t4 + 3][u] = (u > t4 + 3) ? v.w : 0.f;
        }
    }

    // this wave's u-slice of pre-activations, in registers
    float acc[USLICE];
    const float* Sp = S + (size_t)row * M_DIM + j0 + w * USLICE;
#pragma unroll
    for (int q = 0; q < USLICE / 4; ++q) {
        float4 v = *(const float4*)(Sp + q * 4);
        acc[q * 4 + 0] = v.x; acc[q * 4 + 1] = v.y;
        acc[q * 4 + 2] = v.z; acc[q * 4 + 3] = v.w;
    }
    __syncthreads();

    for (int g = 0; g < SEQ_WAVES; ++g) {
        const bool own = (w == g);
#pragma unroll
        for (int s = 0; s < 32; ++s) {
            const int t = (g << 5) + s;
            if (own) {
                float h = tanh_fast(acc[s]);
                acc[s] = h;
                hb[s & 1][lane] = h;
            }
            __syncthreads();
            float h = hb[s & 1][lane];
            const float* wrow = &LW[t][w * USLICE];
#pragma unroll
            for (int j = 0; j < USLICE / 4; ++j) {
                float4 wv = *(const float4*)(wrow + j * 4);
                acc[j * 4 + 0] += wv.x * h;
                acc[j * 4 + 1] += wv.y * h;
                acc[j * 4 + 2] += wv.z * h;
                acc[j * 4 + 3] += wv.w * h;
            }
        }
    }

    // write back h values (each wave writes its slice)
    float* So = S + (size_t)row * M_DIM + j0 + w * USLICE;
#pragma unroll
    for (int q = 0; q < USLICE / 4; ++q) {
        float4 v;
        v.x = acc[q * 4 + 0]; v.y = acc[q * 4 + 1];
        v.z = acc[q * 4 + 2]; v.w = acc[q * 4 + 3];
        *(float4*)(So + q * 4) = v;
    }
}

// ---------------- epilogue: out = sigmoid(S[:, HID : HID+OUT]) --------------
__global__ __launch_bounds__(256)
void out_sigmoid(const float* __restrict__ S, float* __restrict__ out)
{
    int idx = blockIdx.x * blockDim.x + threadIdx.x;
    if (idx >= B_ROWS * OUT_DIM) return;
    int b = idx >> 8;
    int o = idx & (OUT_DIM - 1);
    float y = S[(size_t)b * M_DIM + HID_DIM + o];
    out[idx] = 1.f / (1.f + expf(-y));
}

extern "C" void kernel_launch(void* const* d_in, const int* in_sizes, int n_in,
                              void* d_out, int out_size, void* d_ws, size_t ws_size,
                              hipStream_t stream)
{
    const float* x    = (const float*)d_in[0];   // (8192, 1024)
    const float* W    = (const float*)d_in[1];   // (1280, 2304)
    const float* bias = (const float*)d_in[2];   // (1280,)
    float* out = (float*)d_out;
    float* S   = (float*)d_ws;                   // (8192, 1280) f32 = 41.9 MB

    // 1) S = x @ Wx^T + b  (bf16 MFMA, f32 accumulate)
    gemm_nt_mfma<<<dim3(M_DIM / GBN, B_ROWS / GBM), dim3(256), 0, stream>>>(
        x, IN_DIM, W, P_DIM, S, M_DIM, IN_DIM, bias, 0);

    // 2) blocked triangular recurrence
    for (int J = 0; J < NBLK; ++J) {
        int j0 = J * TBLK;
        seq_block<<<dim3(B_ROWS / 64), dim3(256), 0, stream>>>(S, W, j0);
        int nfut = M_DIM - j0 - TBLK;
        if (nfut > 0) {
            gemm_nt_mfma<<<dim3(nfut / GBN, B_ROWS / GBM), dim3(256), 0, stream>>>(
                S + j0, M_DIM,
                W + (size_t)(j0 + TBLK) * P_DIM + IN_DIM + j0, P_DIM,
                S + j0 + TBLK, M_DIM, TBLK, nullptr, 1);
        }
    }

    // 3) output
    int total = B_ROWS * OUT_DIM;
    out_sigmoid<<<dim3((total + 255) / 256), dim3(256), 0, stream>>>(S, out);
}